// Round 3
// baseline (120.272 us; speedup 1.0000x reference)
//
#include <hip/hip_runtime.h>

// Q=32, S=25, L=64, F=256, H=64
// out[q,s,i,f] = sum_j softmax_j( sum_h tanh(Wq[q,i,h]*Wh[s,j,h]) ) * hs[s,j,f]
// Wq = (qs @ W^T + b) * 2*log2(e)  (pre-scaled: exp2 arg ready), Wh = hs @ W^T + b
// tanh(x) = 1 - 2/(1+exp2(2log2e*x)); per-row constant 64 drops under softmax.
// 4 h-terms share one v_rcp (exp2 arg clamped <= 30: d<=2^61, den<=2^122, safe).
// r8: r6/r7 packing was neutral + VGPR=36 -> NOT issue-bound; LDS-latency-bound
// (loads issued just-in-time, ~120cyc lgkmcnt stall per h4 iter). This round:
// (a) explicit register double-buffer prefetch of all 6 LDS reads per iter,
// (b) 2 i-rows per thread (32-row blocks, grid 1600): 5B->3B LDS per term,
//     8 independent accumulator chains, grid ~fully resident (no 2nd round).
// r9: identical resubmit — r8 bench died on container acquisition (infra).
// total - attn - prep ~= 63-70us is FIXED harness overhead; optimize attn only.

#define NQ 32
#define NS 25
#define NL 64
#define NF 256
#define NH 64

#define K2LOG2E 2.8853900817779268f

typedef __attribute__((ext_vector_type(8))) short bf16x8;
typedef __attribute__((ext_vector_type(4))) float f32x4;
typedef __attribute__((ext_vector_type(2))) float v2f;

__device__ inline unsigned short f2bf(float x) {  // RNE
    union { float f; unsigned int u; } v; v.f = x;
    unsigned int r = v.u + 0x7fffu + ((v.u >> 16) & 1u);
    return (unsigned short)(r >> 16);
}

__device__ inline void cvt_hilo(float4 a, float4 b, bf16x8* hi, bf16x8* lo) {
    float x[8] = {a.x, a.y, a.z, a.w, b.x, b.y, b.z, b.w};
    bf16x8 h8, l8;
#pragma unroll
    for (int i = 0; i < 8; ++i) {
        union { float f; unsigned int u; } v; v.f = x[i];
        unsigned short hh = (unsigned short)(v.u >> 16);
        h8[i] = (short)hh;
        union { unsigned int u; float f; } hf; hf.u = (unsigned int)hh << 16;
        union { float f; unsigned int u; } rv; rv.f = x[i] - hf.f;
        l8[i] = (short)(unsigned short)(rv.u >> 16);
    }
    *hi = h8; *lo = l8;
}

// ---------------- prep kernel (unchanged: ~3-7us, not the bottleneck) ----
#define PROJ_BLOCKS 114
__global__ __launch_bounds__(256) void prep_kernel(
    const float* __restrict__ qs, const float* __restrict__ hs,
    const float* __restrict__ W, const float* __restrict__ b,
    float* __restrict__ Wqs, float* __restrict__ Whs,
    unsigned short* __restrict__ hsT)
{
    __shared__ unsigned short T[64 * 72];
    const int t = threadIdx.x;
    const int bid = blockIdx.x;

    if (bid < PROJ_BLOCKS) {
        const int w = t >> 6, lane = t & 63;
        const int m15 = lane & 15, quad = lane >> 4;
        const int r0 = bid * 32 + (w & 1) * 16;
        const int h0 = (w >> 1) * 32;
        const bool is_q = (r0 < 2048);
        const float* Xrow = is_q ? (qs + (size_t)(r0 + m15) * NF)
                                 : (hs + (size_t)(r0 - 2048 + m15) * NF);
        f32x4 acc[2] = {(f32x4){0.f,0.f,0.f,0.f}, (f32x4){0.f,0.f,0.f,0.f}};

#pragma unroll 2
        for (int kk = 0; kk < 8; ++kk) {
            const int f0 = kk * 32 + quad * 8;
            bf16x8 xhi, xlo;
            cvt_hilo(*(const float4*)(Xrow + f0), *(const float4*)(Xrow + f0 + 4),
                     &xhi, &xlo);
#pragma unroll
            for (int nt = 0; nt < 2; ++nt) {
                const float* Wrow = W + (size_t)(h0 + nt * 16 + m15) * NF + f0;
                bf16x8 whi, wlo;
                cvt_hilo(*(const float4*)(Wrow), *(const float4*)(Wrow + 4),
                         &whi, &wlo);
                acc[nt] = __builtin_amdgcn_mfma_f32_16x16x32_bf16(xhi, whi, acc[nt], 0, 0, 0);
                acc[nt] = __builtin_amdgcn_mfma_f32_16x16x32_bf16(xhi, wlo, acc[nt], 0, 0, 0);
                acc[nt] = __builtin_amdgcn_mfma_f32_16x16x32_bf16(xlo, whi, acc[nt], 0, 0, 0);
            }
        }
#pragma unroll
        for (int nt = 0; nt < 2; ++nt) {
            const int h = h0 + nt * 16 + m15;
            const float bias = b[h];
#pragma unroll
            for (int r = 0; r < 4; ++r) {
                const int row = r0 + quad * 4 + r;
                const float v = acc[nt][r] + bias;
                if (is_q) Wqs[(size_t)row * NH + h] = v * K2LOG2E;
                else      Whs[(size_t)(row - 2048) * NH + h] = v;
            }
        }
    } else {
        const int b2 = bid - PROJ_BLOCKS;
        const int s = b2 >> 2;
        const int f0 = (b2 & 3) * 64;
        const float4* h4p = (const float4*)(hs + (size_t)s * NL * NF);
#pragma unroll
        for (int u = 0; u < 4; ++u) {
            int idx = t + 256 * u;
            int j = idx >> 4, fq = idx & 15;
            float4 v = h4p[j * 64 + (f0 >> 2) + fq];
            T[(4 * fq + 0) * 72 + j] = f2bf(v.x);
            T[(4 * fq + 1) * 72 + j] = f2bf(v.y);
            T[(4 * fq + 2) * 72 + j] = f2bf(v.z);
            T[(4 * fq + 3) * 72 + j] = f2bf(v.w);
        }
        __syncthreads();
#pragma unroll
        for (int u = 0; u < 2; ++u) {
            int idx = t + 256 * u;
            int fl = idx >> 3, jg = idx & 7;
            uint4 v = *(const uint4*)&T[fl * 72 + jg * 8];
            *(uint4*)&hsT[(size_t)(s * 256 + f0 + fl) * 64 + jg * 8] = v;
        }
    }
}

// 8 terms (4 h-values x 2 columns): combine fully packed over the column pair.
// sum accumulates {col0, col1} contributions of sum_h 1/(1+exp2(x)).
__device__ inline void score8(v2f alo, v2f ahi, float4 b0, float4 b1, v2f* sum) {
    const v2f vcl = {30.f, 30.f};
    v2f xlo0 = __builtin_elementwise_min(alo * (v2f){b0.x, b0.y}, vcl);
    v2f xhi0 = __builtin_elementwise_min(ahi * (v2f){b0.z, b0.w}, vcl);
    v2f xlo1 = __builtin_elementwise_min(alo * (v2f){b1.x, b1.y}, vcl);
    v2f xhi1 = __builtin_elementwise_min(ahi * (v2f){b1.z, b1.w}, vcl);
    v2f E0 = { __builtin_amdgcn_exp2f(xlo0[0]), __builtin_amdgcn_exp2f(xlo1[0]) };
    v2f E1 = { __builtin_amdgcn_exp2f(xlo0[1]), __builtin_amdgcn_exp2f(xlo1[1]) };
    v2f E2 = { __builtin_amdgcn_exp2f(xhi0[0]), __builtin_amdgcn_exp2f(xhi1[0]) };
    v2f E3 = { __builtin_amdgcn_exp2f(xhi0[1]), __builtin_amdgcn_exp2f(xhi1[1]) };
    v2f S01 = E0 + E1, S23 = E2 + E3;
    v2f D01 = __builtin_elementwise_fma(E0, E1, S01) + (v2f){1.f, 1.f};
    v2f D23 = __builtin_elementwise_fma(E2, E3, S23) + (v2f){1.f, 1.f};
    v2f U01 = S01 + (v2f){2.f, 2.f};
    v2f U23 = S23 + (v2f){2.f, 2.f};
    v2f NUM = __builtin_elementwise_fma(U01, D23, U23 * D01);
    v2f PROD = D01 * D23;
    v2f R = { __builtin_amdgcn_rcpf(PROD[0]), __builtin_amdgcn_rcpf(PROD[1]) };
    *sum = __builtin_elementwise_fma(NUM, R, *sum);
}

// ---------------- fused attention kernel ----------------
// Grid 1600: (q, s, half). Block: 32 i-rows x 64 j. 256 threads, 2 rows/thread.
// LDS: A f32 [32][68] @0 (8704B) | B f32 [64][68] @2176f (17408B) = 26112B -> 6 blk/CU
//      att bf16 [32][72] (4608B) overlaps A after scores (barrier-guarded).
#define AS 68
#define B_OFF 2176          // floats (32*68)
#define SMEMF 6528          // 26112 B

__global__ __launch_bounds__(256, 6) void attn_kernel(
    const float* __restrict__ Wqs, const float* __restrict__ Whs,
    const unsigned short* __restrict__ hsT, float* __restrict__ out)
{
    __shared__ float smem[SMEMF];
    const int t = threadIdx.x;
    const int bid = blockIdx.x;
    const int qt = bid & 1;
    const int s = (bid >> 1) % NS;
    const int q = bid / (2 * NS);

    // ---- stage A (32x64) and B (64x64), row-major stride 68 ----
    {
        const float4* a4 = (const float4*)(Wqs + ((size_t)q * NL + qt * 32) * NH);
        const float4* b4 = (const float4*)(Whs + (size_t)s * NL * NH);
#pragma unroll
        for (int u = 0; u < 2; ++u) {
            int idx = t + 256 * u;
            int i = idx >> 4, g = idx & 15;
            *(float4*)&smem[i * AS + 4 * g] = a4[idx];
        }
#pragma unroll
        for (int u = 0; u < 4; ++u) {
            int idx = t + 256 * u;
            int j = idx >> 4, g = idx & 15;
            *(float4*)&smem[B_OFF + j * AS + 4 * g] = b4[idx];
        }
    }
    __syncthreads();

    // ---- scores: rows irow & irow+16; col pairs (jn,jn+16),(jn+32,jn+48) ----
    // Register double-buffer: prefetch iter h4+1's 6 float4s before computing h4.
    const int irow = t >> 4;
    const int jn = t & 15;
    v2f s0A = {0.f, 0.f}, s0B = {0.f, 0.f};
    v2f s1A = {0.f, 0.f}, s1B = {0.f, 0.f};
    {
        const float* A0 = &smem[irow * AS];
        const float* A1 = &smem[(irow + 16) * AS];
        const float* Bb = &smem[B_OFF + jn * AS];

        float4 av0 = *(const float4*)(A0);
        float4 av1 = *(const float4*)(A1);
        float4 bv0 = *(const float4*)(Bb);
        float4 bv1 = *(const float4*)(Bb + 16 * AS);
        float4 bv2 = *(const float4*)(Bb + 32 * AS);
        float4 bv3 = *(const float4*)(Bb + 48 * AS);

#pragma unroll 4
        for (int h4 = 0; h4 < 16; ++h4) {
            const int hn = ((h4 + 1) & 15) * 4;   // wraps harmlessly on last iter
            float4 na0 = *(const float4*)(A0 + hn);
            float4 na1 = *(const float4*)(A1 + hn);
            float4 nb0 = *(const float4*)(Bb + hn);
            float4 nb1 = *(const float4*)(Bb + 16 * AS + hn);
            float4 nb2 = *(const float4*)(Bb + 32 * AS + hn);
            float4 nb3 = *(const float4*)(Bb + 48 * AS + hn);

            v2f a0lo = {av0.x, av0.y}, a0hi = {av0.z, av0.w};
            v2f a1lo = {av1.x, av1.y}, a1hi = {av1.z, av1.w};
            score8(a0lo, a0hi, bv0, bv1, &s0A);
            score8(a0lo, a0hi, bv2, bv3, &s0B);
            score8(a1lo, a1hi, bv0, bv1, &s1A);
            score8(a1lo, a1hi, bv2, bv3, &s1B);

            av0 = na0; av1 = na1;
            bv0 = nb0; bv1 = nb1; bv2 = nb2; bv3 = nb3;
        }
    }
    __syncthreads();  // all A/B reads complete before att overwrites A region

    // ---- in-wave softmax over j for both rows (min-form) ----
    {
        float sum0[4] = {s0A[0], s0A[1], s0B[0], s0B[1]};  // row irow,    cols jn+16*jj
        float sum1[4] = {s1A[0], s1A[1], s1B[0], s1B[1]};  // row irow+16, cols jn+16*jj
        float mn0 = fminf(fminf(sum0[0], sum0[1]), fminf(sum0[2], sum0[3]));
        float mn1 = fminf(fminf(sum1[0], sum1[1]), fminf(sum1[2], sum1[3]));
        mn0 = fminf(mn0, __shfl_xor(mn0, 1));
        mn1 = fminf(mn1, __shfl_xor(mn1, 1));
        mn0 = fminf(mn0, __shfl_xor(mn0, 2));
        mn1 = fminf(mn1, __shfl_xor(mn1, 2));
        mn0 = fminf(mn0, __shfl_xor(mn0, 4));
        mn1 = fminf(mn1, __shfl_xor(mn1, 4));
        mn0 = fminf(mn0, __shfl_xor(mn0, 8));
        mn1 = fminf(mn1, __shfl_xor(mn1, 8));
        float p0[4], p1[4];
        float d0 = 0.f, d1 = 0.f;
#pragma unroll
        for (int jj = 0; jj < 4; ++jj) {
            p0[jj] = __builtin_amdgcn_exp2f((mn0 - sum0[jj]) * K2LOG2E);
            p1[jj] = __builtin_amdgcn_exp2f((mn1 - sum1[jj]) * K2LOG2E);
            d0 += p0[jj];
            d1 += p1[jj];
        }
        d0 += __shfl_xor(d0, 1);
        d1 += __shfl_xor(d1, 1);
        d0 += __shfl_xor(d0, 2);
        d1 += __shfl_xor(d1, 2);
        d0 += __shfl_xor(d0, 4);
        d1 += __shfl_xor(d1, 4);
        d0 += __shfl_xor(d0, 8);
        d1 += __shfl_xor(d1, 8);
        const float inv0 = __builtin_amdgcn_rcpf(d0);
        const float inv1 = __builtin_amdgcn_rcpf(d1);
        unsigned short* att = (unsigned short*)smem;  // [32][72] bf16 over dead A
#pragma unroll
        for (int jj = 0; jj < 4; ++jj) {
            att[irow * 72 + jn + 16 * jj] = f2bf(p0[jj] * inv0);
            att[(irow + 16) * 72 + jn + 16 * jj] = f2bf(p1[jj] * inv1);
        }
    }
    __syncthreads();

    // ---- PV via bf16 MFMA: [32 x 64j] @ [64j x 256f]; wave wv -> f-tiles wv*4.. ----
    const int lane = t & 63;
    const int wv = t >> 6;
    const int m15 = lane & 15;
    const int quad = lane >> 4;

    bf16x8 afr[2][2];  // [m-tile][k]: A[m*16 + (lane&15)][k=quad*8+idx]
#pragma unroll
    for (int m = 0; m < 2; ++m)
#pragma unroll
        for (int k = 0; k < 2; ++k)
            afr[m][k] = *(const bf16x8*)((const char*)smem
                            + (m * 16 + m15) * 144 + k * 64 + quad * 16);

    const unsigned short* hsTs = hsT + (size_t)s * NF * NL;
    f32x4 acc[2][4];
#pragma unroll
    for (int m = 0; m < 2; ++m)
#pragma unroll
        for (int n = 0; n < 4; ++n) acc[m][n] = (f32x4){0.f, 0.f, 0.f, 0.f};

#pragma unroll
    for (int k = 0; k < 2; ++k) {
        bf16x8 bfr[4];  // B[k][n=lane&15]: hsT row f, 8 consecutive j
#pragma unroll
        for (int n = 0; n < 4; ++n)
            bfr[n] = *(const bf16x8*)(hsTs
                        + (size_t)((wv * 4 + n) * 16 + m15) * 64 + k * 32 + quad * 8);
#pragma unroll
        for (int n = 0; n < 4; ++n) {
            acc[0][n] = __builtin_amdgcn_mfma_f32_16x16x32_bf16(afr[0][k], bfr[n], acc[0][n], 0, 0, 0);
            acc[1][n] = __builtin_amdgcn_mfma_f32_16x16x32_bf16(afr[1][k], bfr[n], acc[1][n], 0, 0, 0);
        }
    }

    // C layout: col(f) = lane&15, row(i) = m*16 + quad*4 + reg
    const size_t obase = ((size_t)(q * NS + s) * NL + qt * 32) * NF;
#pragma unroll
    for (int m = 0; m < 2; ++m)
#pragma unroll
        for (int n = 0; n < 4; ++n)
#pragma unroll
            for (int r = 0; r < 4; ++r)
                out[obase + (size_t)(m * 16 + quad * 4 + r) * NF
                    + (wv * 4 + n) * 16 + m15] = acc[m][n][r];
}

extern "C" void kernel_launch(void* const* d_in, const int* in_sizes, int n_in,
                              void* d_out, int out_size, void* d_ws, size_t ws_size,
                              hipStream_t stream) {
    const float* qs = (const float*)d_in[0];
    const float* hs = (const float*)d_in[1];
    const float* W  = (const float*)d_in[2];
    const float* b  = (const float*)d_in[3];
    float* out = (float*)d_out;

    float* Wqs = (float*)d_ws;                         // 131072 f
    float* Whs = Wqs + NQ * NL * NH;                   // 102400 f
    unsigned short* hsT = (unsigned short*)(Whs + NS * NL * NH);  // 409600 bf16

    prep_kernel<<<PROJ_BLOCKS + NS * 4, 256, 0, stream>>>(qs, hs, W, b, Wqs, Whs, hsT);
    attn_kernel<<<NQ * NS * 2, 256, 0, stream>>>(Wqs, Whs, hsT, out);
}

// Round 4
// 118.039 us; speedup vs baseline: 1.0189x; 1.0189x over previous
//
#include <hip/hip_runtime.h>

// Q=32, S=25, L=64, F=256, H=64
// out[q,s,i,f] = sum_j softmax_j( sum_h tanh(Wq[q,i,h]*Wh[s,j,h]) ) * hs[s,j,f]
// Wq = (qs @ W^T + b) * 2*log2(e)  (pre-scaled: exp2 arg ready), Wh = hs @ W^T + b
// tanh(x) = 1 - 2/(1+exp2(2log2e*x)); per-row constant 64 drops under softmax.
// 4 h-terms share one v_rcp (exp2 arg clamped <= 30: d<=2^61, den<=2^122, safe).
// r10: r6-r9 all ~48-50us vs ~14us issue floor, VALU idle ~39%, VGPR stuck at
// 36-40 -> compiler serializes the independent score chains (saves regs, eats
// exp2/rcp chain latency ~50cyc/call). Fix: stage-fused score16 — all 8 pk_mul,
// all mins, ALL 16 exp2 adjacent (latency hidden by sibling issue), packed
// combine, 4 adjacent rcps. Geometry restored to r7 (best measured: 48.0us,
// grid 3200, 22KB LDS, 7 blk/CU). Math identical to r7 -> absmax unchanged.
// total - attn - prep ~= 63-70us is FIXED harness overhead; optimize attn only.

#define NQ 32
#define NS 25
#define NL 64
#define NF 256
#define NH 64

#define K2LOG2E 2.8853900817779268f

typedef __attribute__((ext_vector_type(8))) short bf16x8;
typedef __attribute__((ext_vector_type(4))) float f32x4;
typedef __attribute__((ext_vector_type(2))) float v2f;

__device__ inline unsigned short f2bf(float x) {  // RNE
    union { float f; unsigned int u; } v; v.f = x;
    unsigned int r = v.u + 0x7fffu + ((v.u >> 16) & 1u);
    return (unsigned short)(r >> 16);
}

__device__ inline void cvt_hilo(float4 a, float4 b, bf16x8* hi, bf16x8* lo) {
    float x[8] = {a.x, a.y, a.z, a.w, b.x, b.y, b.z, b.w};
    bf16x8 h8, l8;
#pragma unroll
    for (int i = 0; i < 8; ++i) {
        union { float f; unsigned int u; } v; v.f = x[i];
        unsigned short hh = (unsigned short)(v.u >> 16);
        h8[i] = (short)hh;
        union { unsigned int u; float f; } hf; hf.u = (unsigned int)hh << 16;
        union { float f; unsigned int u; } rv; rv.f = x[i] - hf.f;
        l8[i] = (short)(unsigned short)(rv.u >> 16);
    }
    *hi = h8; *lo = l8;
}

// ---------------- prep kernel (unchanged: ~3-7us, not the bottleneck) ----
#define PROJ_BLOCKS 114
__global__ __launch_bounds__(256) void prep_kernel(
    const float* __restrict__ qs, const float* __restrict__ hs,
    const float* __restrict__ W, const float* __restrict__ b,
    float* __restrict__ Wqs, float* __restrict__ Whs,
    unsigned short* __restrict__ hsT)
{
    __shared__ unsigned short T[64 * 72];
    const int t = threadIdx.x;
    const int bid = blockIdx.x;

    if (bid < PROJ_BLOCKS) {
        const int w = t >> 6, lane = t & 63;
        const int m15 = lane & 15, quad = lane >> 4;
        const int r0 = bid * 32 + (w & 1) * 16;
        const int h0 = (w >> 1) * 32;
        const bool is_q = (r0 < 2048);
        const float* Xrow = is_q ? (qs + (size_t)(r0 + m15) * NF)
                                 : (hs + (size_t)(r0 - 2048 + m15) * NF);
        f32x4 acc[2] = {(f32x4){0.f,0.f,0.f,0.f}, (f32x4){0.f,0.f,0.f,0.f}};

#pragma unroll 2
        for (int kk = 0; kk < 8; ++kk) {
            const int f0 = kk * 32 + quad * 8;
            bf16x8 xhi, xlo;
            cvt_hilo(*(const float4*)(Xrow + f0), *(const float4*)(Xrow + f0 + 4),
                     &xhi, &xlo);
#pragma unroll
            for (int nt = 0; nt < 2; ++nt) {
                const float* Wrow = W + (size_t)(h0 + nt * 16 + m15) * NF + f0;
                bf16x8 whi, wlo;
                cvt_hilo(*(const float4*)(Wrow), *(const float4*)(Wrow + 4),
                         &whi, &wlo);
                acc[nt] = __builtin_amdgcn_mfma_f32_16x16x32_bf16(xhi, whi, acc[nt], 0, 0, 0);
                acc[nt] = __builtin_amdgcn_mfma_f32_16x16x32_bf16(xhi, wlo, acc[nt], 0, 0, 0);
                acc[nt] = __builtin_amdgcn_mfma_f32_16x16x32_bf16(xlo, whi, acc[nt], 0, 0, 0);
            }
        }
#pragma unroll
        for (int nt = 0; nt < 2; ++nt) {
            const int h = h0 + nt * 16 + m15;
            const float bias = b[h];
#pragma unroll
            for (int r = 0; r < 4; ++r) {
                const int row = r0 + quad * 4 + r;
                const float v = acc[nt][r] + bias;
                if (is_q) Wqs[(size_t)row * NH + h] = v * K2LOG2E;
                else      Whs[(size_t)(row - 2048) * NH + h] = v;
            }
        }
    } else {
        const int b2 = bid - PROJ_BLOCKS;
        const int s = b2 >> 2;
        const int f0 = (b2 & 3) * 64;
        const float4* h4p = (const float4*)(hs + (size_t)s * NL * NF);
#pragma unroll
        for (int u = 0; u < 4; ++u) {
            int idx = t + 256 * u;
            int j = idx >> 4, fq = idx & 15;
            float4 v = h4p[j * 64 + (f0 >> 2) + fq];
            T[(4 * fq + 0) * 72 + j] = f2bf(v.x);
            T[(4 * fq + 1) * 72 + j] = f2bf(v.y);
            T[(4 * fq + 2) * 72 + j] = f2bf(v.z);
            T[(4 * fq + 3) * 72 + j] = f2bf(v.w);
        }
        __syncthreads();
#pragma unroll
        for (int u = 0; u < 2; ++u) {
            int idx = t + 256 * u;
            int fl = idx >> 3, jg = idx & 7;
            uint4 v = *(const uint4*)&T[fl * 72 + jg * 8];
            *(uint4*)&hsT[(size_t)(s * 256 + f0 + fl) * 64 + jg * 8] = v;
        }
    }
}

// 16 terms (4 h x 4 cols) in explicit stages so the scheduler cannot serialize:
// stage1: 8 pk_mul + mins, stage2: 16 independent exp2 back-to-back (trans
// latency hidden by sibling issue), stage3: packed combine over column pairs,
// 4 adjacent rcps. Math identical to the r7 score8 pair.
__device__ inline void score16(v2f alo, v2f ahi,
                               float4 b0, float4 b1, float4 b2, float4 b3,
                               v2f* sA, v2f* sB)
{
    const v2f vcl = {30.f, 30.f};
    // stage 1: products + clamp. xlN/xhN = {h0,h1} / {h2,h3} of column N.
    v2f xl0 = __builtin_elementwise_min(alo * (v2f){b0.x, b0.y}, vcl);
    v2f xh0 = __builtin_elementwise_min(ahi * (v2f){b0.z, b0.w}, vcl);
    v2f xl1 = __builtin_elementwise_min(alo * (v2f){b1.x, b1.y}, vcl);
    v2f xh1 = __builtin_elementwise_min(ahi * (v2f){b1.z, b1.w}, vcl);
    v2f xl2 = __builtin_elementwise_min(alo * (v2f){b2.x, b2.y}, vcl);
    v2f xh2 = __builtin_elementwise_min(ahi * (v2f){b2.z, b2.w}, vcl);
    v2f xl3 = __builtin_elementwise_min(alo * (v2f){b3.x, b3.y}, vcl);
    v2f xh3 = __builtin_elementwise_min(ahi * (v2f){b3.z, b3.w}, vcl);
    // stage 2: all 16 exp2 (mutually independent)
    float e00 = __builtin_amdgcn_exp2f(xl0[0]);
    float e10 = __builtin_amdgcn_exp2f(xl0[1]);
    float e20 = __builtin_amdgcn_exp2f(xh0[0]);
    float e30 = __builtin_amdgcn_exp2f(xh0[1]);
    float e01 = __builtin_amdgcn_exp2f(xl1[0]);
    float e11 = __builtin_amdgcn_exp2f(xl1[1]);
    float e21 = __builtin_amdgcn_exp2f(xh1[0]);
    float e31 = __builtin_amdgcn_exp2f(xh1[1]);
    float e02 = __builtin_amdgcn_exp2f(xl2[0]);
    float e12 = __builtin_amdgcn_exp2f(xl2[1]);
    float e22 = __builtin_amdgcn_exp2f(xh2[0]);
    float e32 = __builtin_amdgcn_exp2f(xh2[1]);
    float e03 = __builtin_amdgcn_exp2f(xl3[0]);
    float e13 = __builtin_amdgcn_exp2f(xl3[1]);
    float e23 = __builtin_amdgcn_exp2f(xh3[0]);
    float e33 = __builtin_amdgcn_exp2f(xh3[1]);
    // stage 3: packed combine over column pairs (0,1)->sA and (2,3)->sB
    v2f E0A = {e00, e01}, E1A = {e10, e11}, E2A = {e20, e21}, E3A = {e30, e31};
    v2f E0B = {e02, e03}, E1B = {e12, e13}, E2B = {e22, e23}, E3B = {e32, e33};
    v2f S01A = E0A + E1A, S23A = E2A + E3A;
    v2f S01B = E0B + E1B, S23B = E2B + E3B;
    v2f one = {1.f, 1.f}, two = {2.f, 2.f};
    v2f D01A = __builtin_elementwise_fma(E0A, E1A, S01A) + one;
    v2f D23A = __builtin_elementwise_fma(E2A, E3A, S23A) + one;
    v2f D01B = __builtin_elementwise_fma(E0B, E1B, S01B) + one;
    v2f D23B = __builtin_elementwise_fma(E2B, E3B, S23B) + one;
    v2f NUMA = __builtin_elementwise_fma(S01A + two, D23A, (S23A + two) * D01A);
    v2f NUMB = __builtin_elementwise_fma(S01B + two, D23B, (S23B + two) * D01B);
    v2f PA = D01A * D23A, PB = D01B * D23B;
    v2f RA = { __builtin_amdgcn_rcpf(PA[0]), __builtin_amdgcn_rcpf(PA[1]) };
    v2f RB = { __builtin_amdgcn_rcpf(PB[0]), __builtin_amdgcn_rcpf(PB[1]) };
    *sA = __builtin_elementwise_fma(NUMA, RA, *sA);
    *sB = __builtin_elementwise_fma(NUMB, RB, *sB);
}

// ---------------- fused attention kernel ----------------
// Grid 3200: (q, s, quarter). Block: 16 i-rows x 64 j. 256 threads.
// LDS: A f32 [16][68] @0 (4352B) | B f32 [64][68] @4352B (17408B) = 21760B -> 7 blk/CU
//      att bf16 [16][72] overlaps A after scores (barrier-guarded).
#define AS 68
#define B_OFF 1088          // floats (16*68)
#define SMEMF 5440          // 21760 B

__global__ __launch_bounds__(256, 7) void attn_kernel(
    const float* __restrict__ Wqs, const float* __restrict__ Whs,
    const unsigned short* __restrict__ hsT, float* __restrict__ out)
{
    __shared__ float smem[SMEMF];
    const int t = threadIdx.x;
    const int bid = blockIdx.x;
    const int qt = bid & 3;
    const int s = (bid >> 2) % NS;
    const int q = bid / (4 * NS);

    // ---- stage A (16x64) and B (64x64), row-major stride 68 ----
    {
        const float4* a4 = (const float4*)(Wqs + ((size_t)q * NL + qt * 16) * NH);
        const float4* b4 = (const float4*)(Whs + (size_t)s * NL * NH);
        {
            int i = t >> 4, g = t & 15;
            *(float4*)&smem[i * AS + 4 * g] = a4[t];
        }
#pragma unroll
        for (int u = 0; u < 4; ++u) {
            int idx = t + 256 * u;
            int j = idx >> 4, g = idx & 15;
            *(float4*)&smem[B_OFF + j * AS + 4 * g] = b4[idx];
        }
    }
    __syncthreads();

    // ---- scores: row i = t>>4, cols jn+16*jj ----
    const int irow = t >> 4;
    const int jn = t & 15;
    v2f sumA = {0.f, 0.f}, sumB = {0.f, 0.f};
    {
        const float* Ab = &smem[irow * AS];
        const float* Bb = &smem[B_OFF + jn * AS];

#pragma unroll 4
        for (int h4 = 0; h4 < 16; ++h4) {
            float4 av = *(const float4*)(Ab + 4 * h4);
            v2f alo = {av.x, av.y}, ahi = {av.z, av.w};
            float4 b0 = *(const float4*)(Bb + 4 * h4);
            float4 b1 = *(const float4*)(Bb + 16 * AS + 4 * h4);
            float4 b2 = *(const float4*)(Bb + 32 * AS + 4 * h4);
            float4 b3 = *(const float4*)(Bb + 48 * AS + 4 * h4);
            score16(alo, ahi, b0, b1, b2, b3, &sumA, &sumB);
        }
    }
    __syncthreads();  // all A/B reads complete before att overwrites A region

    // ---- in-wave softmax over j (min-form: score = -2*sum + const) ----
    {
        float sum[4] = {sumA[0], sumA[1], sumB[0], sumB[1]};  // cols jn+16*jj
        float mn = fminf(fminf(sum[0], sum[1]), fminf(sum[2], sum[3]));
        mn = fminf(mn, __shfl_xor(mn, 1));
        mn = fminf(mn, __shfl_xor(mn, 2));
        mn = fminf(mn, __shfl_xor(mn, 4));
        mn = fminf(mn, __shfl_xor(mn, 8));
        float p[4];
        float d = 0.f;
#pragma unroll
        for (int jj = 0; jj < 4; ++jj) {
            p[jj] = __builtin_amdgcn_exp2f((mn - sum[jj]) * K2LOG2E);
            d += p[jj];
        }
        d += __shfl_xor(d, 1);
        d += __shfl_xor(d, 2);
        d += __shfl_xor(d, 4);
        d += __shfl_xor(d, 8);
        const float inv = __builtin_amdgcn_rcpf(d);
        unsigned short* att = (unsigned short*)smem;  // [16][72] bf16 over dead A
#pragma unroll
        for (int jj = 0; jj < 4; ++jj)
            att[irow * 72 + jn + 16 * jj] = f2bf(p[jj] * inv);
    }
    __syncthreads();

    // ---- PV via bf16 MFMA: [16 x 64j] @ [64j x 256f]; wave wv -> f-tiles wv*4.. ----
    const int lane = t & 63;
    const int wv = t >> 6;
    const int m15 = lane & 15;
    const int quad = lane >> 4;

    bf16x8 afr[2];  // A[m=lane&15][k=quad*8+idx]
#pragma unroll
    for (int k = 0; k < 2; ++k)
        afr[k] = *(const bf16x8*)((const char*)smem + m15 * 144 + k * 64 + quad * 16);

    const unsigned short* hsTs = hsT + (size_t)s * NF * NL;
    f32x4 acc[4];
#pragma unroll
    for (int n = 0; n < 4; ++n) acc[n] = (f32x4){0.f, 0.f, 0.f, 0.f};

#pragma unroll
    for (int k = 0; k < 2; ++k) {
        bf16x8 bfr[4];  // B[k][n=lane&15]: hsT row f, 8 consecutive j
#pragma unroll
        for (int n = 0; n < 4; ++n)
            bfr[n] = *(const bf16x8*)(hsTs
                        + (size_t)((wv * 4 + n) * 16 + m15) * 64 + k * 32 + quad * 8);
#pragma unroll
        for (int n = 0; n < 4; ++n)
            acc[n] = __builtin_amdgcn_mfma_f32_16x16x32_bf16(afr[k], bfr[n], acc[n], 0, 0, 0);
    }

    // C layout: col(f) = lane&15, row(i) = quad*4 + reg
    const size_t obase = ((size_t)(q * NS + s) * NL + qt * 16) * NF;
#pragma unroll
    for (int n = 0; n < 4; ++n)
#pragma unroll
        for (int r = 0; r < 4; ++r)
            out[obase + (size_t)(quad * 4 + r) * NF + (wv * 4 + n) * 16 + m15] = acc[n][r];
}

extern "C" void kernel_launch(void* const* d_in, const int* in_sizes, int n_in,
                              void* d_out, int out_size, void* d_ws, size_t ws_size,
                              hipStream_t stream) {
    const float* qs = (const float*)d_in[0];
    const float* hs = (const float*)d_in[1];
    const float* W  = (const float*)d_in[2];
    const float* b  = (const float*)d_in[3];
    float* out = (float*)d_out;

    float* Wqs = (float*)d_ws;                         // 131072 f
    float* Whs = Wqs + NQ * NL * NH;                   // 102400 f
    unsigned short* hsT = (unsigned short*)(Whs + NS * NL * NH);  // 409600 bf16

    prep_kernel<<<PROJ_BLOCKS + NS * 4, 256, 0, stream>>>(qs, hs, W, b, Wqs, Whs, hsT);
    attn_kernel<<<NQ * NS * 4, 256, 0, stream>>>(Wqs, Whs, hsT, out);
}